// Round 8
// baseline (316.893 us; speedup 1.0000x reference)
//
#include <hip/hip_runtime.h>
#include <hip/hip_bf16.h>
#include <cstdint>
#include <cstddef>

// Problem constants
#define NB   64
#define NS   8
#define DIM  2048
#define FF   4096
#define NE   8
#define TOK  512            // NB*NS
#define NPAIR 1024          // TOK*2

// GEMM tiling
#define BM   192            // M capacity per pass (Binomial(512,1/4): mean 128, +6.5 sigma)
#define BKE  64             // K per epoch (2 MFMA K-slices per barrier)

typedef __attribute__((ext_vector_type(4))) float f32x4;
typedef __attribute__((ext_vector_type(8))) short bf16x8;
typedef __attribute__((ext_vector_type(4))) short bf16x4;

#define MFMA16(a, b, c) __builtin_amdgcn_mfma_f32_16x16x32_bf16((a), (b), (c), 0, 0, 0)
#define SCHEDBAR __builtin_amdgcn_sched_barrier(0)

// round-half-up fp32 -> bf16 (0.5 ulp, 2 VALU ops)
static __device__ __forceinline__ short f2bf(float f) {
    unsigned u = __builtin_bit_cast(unsigned, f);
    return (short)((u + 0x8000u) >> 16);
}

// ---------------------------------------------------------------------------
// Kernel 1: gating (logits -> top-2 -> softmax) + x -> bf16 preconvert.
// ---------------------------------------------------------------------------
__global__ void gate_topk(const float* __restrict__ x, const float* __restrict__ gw,
                          unsigned short* __restrict__ xbf,
                          int* __restrict__ tok_expert, float* __restrict__ tok_gatew) {
    int token = blockIdx.x;
    int lane  = threadIdx.x;
    const float* xr = x + (size_t)token * DIM;

    float acc[NE];
#pragma unroll
    for (int e = 0; e < NE; ++e) acc[e] = 0.f;

    for (int d0 = lane * 8; d0 < DIM; d0 += 64 * 8) {
        float4 xa = *(const float4*)(xr + d0);
        float4 xb = *(const float4*)(xr + d0 + 4);
        bf16x8 v;
        v[0] = f2bf(xa.x); v[1] = f2bf(xa.y); v[2] = f2bf(xa.z); v[3] = f2bf(xa.w);
        v[4] = f2bf(xb.x); v[5] = f2bf(xb.y); v[6] = f2bf(xb.z); v[7] = f2bf(xb.w);
        *(bf16x8*)(xbf + (size_t)token * DIM + d0) = v;
#pragma unroll
        for (int j = 0; j < 8; ++j) {
            float xv = (j < 4) ? ((const float*)&xa)[j] : ((const float*)&xb)[j - 4];
            const float4* g = (const float4*)(gw + (size_t)(d0 + j) * NE);
            float4 g0 = g[0], g1 = g[1];
            acc[0] += xv * g0.x; acc[1] += xv * g0.y;
            acc[2] += xv * g0.z; acc[3] += xv * g0.w;
            acc[4] += xv * g1.x; acc[5] += xv * g1.y;
            acc[6] += xv * g1.z; acc[7] += xv * g1.w;
        }
    }
#pragma unroll
    for (int off = 32; off >= 1; off >>= 1) {
#pragma unroll
        for (int e = 0; e < NE; ++e) acc[e] += __shfl_down(acc[e], off);
    }
    if (lane == 0) {
        float b1 = -1e30f, b2 = -1e30f; int i1 = 0, i2 = 0;
#pragma unroll
        for (int e = 0; e < NE; ++e) {
            float v = acc[e];
            if (v > b1) { b2 = b1; i2 = i1; b1 = v; i1 = e; }
            else if (v > b2) { b2 = v; i2 = e; }
        }
        float t = __expf(b2 - b1);
        tok_expert[token * 2 + 0] = i1;
        tok_expert[token * 2 + 1] = i2;
        tok_gatew[token * 2 + 0] = 1.f / (1.f + t);
        tok_gatew[token * 2 + 1] = t / (1.f + t);
    }
}

// ---------------------------------------------------------------------------
// Kernel 2: deterministic per-expert token lists (wave-per-expert ballot scan)
// ---------------------------------------------------------------------------
__global__ void build_lists(const int* __restrict__ tok_expert,
                            const float* __restrict__ tok_gatew,
                            int* __restrict__ counts, int* __restrict__ offsets,
                            int* __restrict__ row_token, float* __restrict__ row_gatew,
                            int* __restrict__ pair_row) {
    __shared__ int s_off[NE];
    __shared__ int s_cnt[NE];
    int e    = threadIdx.x >> 6;
    int lane = threadIdx.x & 63;
    unsigned long long lt = (1ull << lane) - 1ull;

    int cnt = 0;
    for (int base = 0; base < NPAIR; base += 64) {
        int id = tok_expert[base + lane];
        unsigned long long m = __ballot(id == e);
        cnt += __popcll(m);
    }
    if (lane == 0) s_cnt[e] = cnt;
    __syncthreads();
    if (threadIdx.x == 0) {
        int o = 0;
        for (int i = 0; i < NE; ++i) {
            int c = s_cnt[i];
            counts[i] = c; offsets[i] = o; s_off[i] = o; o += c;
        }
    }
    __syncthreads();

    int rbase = s_off[e];
    for (int base = 0; base < NPAIR; base += 64) {
        int entry = base + lane;
        int id = tok_expert[entry];
        bool match = (id == e);
        unsigned long long m = __ballot(match);
        int pre = __popcll(m & lt);
        if (match) {
            int row = rbase + pre;
            row_token[row] = entry >> 1;
            row_gatew[row] = tok_gatew[entry];
            pair_row[entry] = row;
        }
        rbase += __popcll(m);
    }
}

// ---------------------------------------------------------------------------
// Kernel 3: H = silu(Xbf*w1) .* (Xbf*w3).  grid = 8 x 64 f-tiles (BN=64),
// 512 thr = 8 waves (4M x 2N).  Per epoch (BKE=64):
//   [A gathers for THIS epoch] schedbar [B reg-loads for NEXT epoch]
//   [MFMA: auto counted-vmcnt leaves B in flight] [cvt+ds_write B] [barrier]
// No hand vmcnt; compiler's FIFO waits are exact with this issue order.
// ---------------------------------------------------------------------------
__global__ __launch_bounds__(512, 4) void ffn1(
    const unsigned short* __restrict__ xbf, const float* __restrict__ w1,
    const float* __restrict__ w3,
    const int* __restrict__ counts, const int* __restrict__ offsets,
    const int* __restrict__ row_token, unsigned short* __restrict__ Hbuf) {
    // [buf][mat][slice][chunk 256][8] : chunk = col + klg*64  (conflict-free)
    __shared__ __align__(16) unsigned short Bs[2][2][2][256][8];   // 32 KB

    int bid = blockIdx.x;
    int e  = bid >> 6;
    int f0 = (bid & 63) * 64;

    int Me = counts[e];
    if (Me == 0) return;
    int off = offsets[e];

    int t = threadIdx.x;
    int lane = t & 63;
    int w = t >> 6;
    int wm = w >> 1, wn = w & 1;                 // 4 M-waves x 2 N-waves
    int l15 = lane & 15, lg = lane >> 4;

    const float* w1e = w1 + (size_t)e * DIM * FF + f0;
    const float* w3e = w3 + (size_t)e * DIM * FF + f0;

    // B staging role: (bmat, blg, bcol); 16 fp32 coalesced loads/epoch
    int bcol = t & 63, blg = (t >> 6) & 3, bmat = t >> 8;
    const float* bsrc = (bmat ? w3e : w1e) + (size_t)(blg * 8) * FF + bcol;
    int bch = blg * 64 + bcol;

    const int NST = DIM / BKE;                   // 32 epochs

    for (int mb = 0; mb < Me; mb += BM) {
        const unsigned short* arow[3];
#pragma unroll
        for (int f = 0; f < 3; ++f) {
            int rl = mb + wm * 48 + f * 16 + l15;
            int rr = (rl < Me) ? rl : (Me - 1);
            arow[f] = xbf + (size_t)row_token[off + rr] * DIM + lg * 8;
        }

        f32x4 acc1[3][2], acc3[3][2];
#pragma unroll
        for (int f = 0; f < 3; ++f)
#pragma unroll
            for (int nf = 0; nf < 2; ++nf) {
                acc1[f][nf] = (f32x4){0.f, 0.f, 0.f, 0.f};
                acc3[f][nf] = (f32x4){0.f, 0.f, 0.f, 0.f};
            }

        float bR[16];
        // prologue: B(epoch 0) -> regs -> cvt -> Bs[0]
#pragma unroll
        for (int u = 0; u < 16; ++u) {
            int sl = u >> 3, j = u & 7;
            bR[u] = bsrc[(size_t)(sl * 32 + j) * FF];
        }
        {
            bf16x8 wv0, wv1;
#pragma unroll
            for (int j = 0; j < 8; ++j) { wv0[j] = f2bf(bR[j]); wv1[j] = f2bf(bR[8 + j]); }
            *(bf16x8*)&Bs[0][bmat][0][bch][0] = wv0;
            *(bf16x8*)&Bs[0][bmat][1][bch][0] = wv1;
        }
        __syncthreads();

        for (int s = 0; s < NST; ++s) {
            int cur = s & 1;
            bool more = (s + 1 < NST);

            // 1) A gathers for THIS epoch (issued first => counted waits work)
            bf16x8 aE[3], aO[3];
#pragma unroll
            for (int f = 0; f < 3; ++f) aE[f] = *(const bf16x8*)(arow[f] + s * BKE);
#pragma unroll
            for (int f = 0; f < 3; ++f) aO[f] = *(const bf16x8*)(arow[f] + s * BKE + 32);
            SCHEDBAR;    // pin: A issued before B (vmcnt FIFO)

            // 2) B loads for NEXT epoch (stay in flight through the MFMAs)
            if (more) {
#pragma unroll
                for (int u = 0; u < 16; ++u) {
                    int sl = u >> 3, j = u & 7;
                    bR[u] = bsrc[(size_t)((s + 1) * BKE + sl * 32 + j) * FF];
                }
            }

            // 3) MFMAs (slice 0 then slice 1)
#pragma unroll
            for (int nf = 0; nf < 2; ++nf) {
                int ch = wn * 32 + nf * 16 + l15 + lg * 64;
                bf16x8 b1f = *(const bf16x8*)&Bs[cur][0][0][ch][0];
                bf16x8 b3f = *(const bf16x8*)&Bs[cur][1][0][ch][0];
#pragma unroll
                for (int f = 0; f < 3; ++f) {
                    acc1[f][nf] = MFMA16(aE[f], b1f, acc1[f][nf]);
                    acc3[f][nf] = MFMA16(aE[f], b3f, acc3[f][nf]);
                }
            }
#pragma unroll
            for (int nf = 0; nf < 2; ++nf) {
                int ch = wn * 32 + nf * 16 + l15 + lg * 64;
                bf16x8 b1f = *(const bf16x8*)&Bs[cur][0][1][ch][0];
                bf16x8 b3f = *(const bf16x8*)&Bs[cur][1][1][ch][0];
#pragma unroll
                for (int f = 0; f < 3; ++f) {
                    acc1[f][nf] = MFMA16(aO[f], b1f, acc1[f][nf]);
                    acc3[f][nf] = MFMA16(aO[f], b3f, acc3[f][nf]);
                }
            }

            // 4) cvt + write next-epoch B into the other buffer
            if (more) {
                bf16x8 wv0, wv1;
#pragma unroll
                for (int j = 0; j < 8; ++j) { wv0[j] = f2bf(bR[j]); wv1[j] = f2bf(bR[8 + j]); }
                *(bf16x8*)&Bs[cur ^ 1][bmat][0][bch][0] = wv0;
                *(bf16x8*)&Bs[cur ^ 1][bmat][1][bch][0] = wv1;
            }
            __syncthreads();   // free: all vm/lds ops already consumed
        }

        // epilogue: silu(a1)*a3 -> bf16 H
#pragma unroll
        for (int f = 0; f < 3; ++f)
#pragma unroll
            for (int nf = 0; nf < 2; ++nf)
#pragma unroll
                for (int r = 0; r < 4; ++r) {
                    int rl = mb + wm * 48 + f * 16 + lg * 4 + r;
                    if (rl < Me) {
                        float a1 = acc1[f][nf][r], a3 = acc3[f][nf][r];
                        float h = (a1 / (1.f + __expf(-a1))) * a3;
                        Hbuf[(size_t)(off + rl) * FF + f0 + wn * 32 + nf * 16 + l15] =
                            (unsigned short)f2bf(h);
                    }
                }
    }
}

// ---------------------------------------------------------------------------
// Kernel 4: OutPair = (H @ w2) * gate_weight.  grid = 8 x 64 d-tiles (BN=32),
// 512 thr, 2 blocks/CU.  Same epoch structure; A gathers from Hbuf (L2-warm).
// ---------------------------------------------------------------------------
__global__ __launch_bounds__(512, 4) void ffn2(
    const unsigned short* __restrict__ Hbuf, const float* __restrict__ w2,
    const int* __restrict__ counts, const int* __restrict__ offsets,
    const float* __restrict__ row_gatew, float* __restrict__ OP) {
    // [buf][slice][chunk 128][8] : chunk = col + klg*32
    __shared__ __align__(16) unsigned short Bs[2][2][128][8];      // 8 KB

    int bid = blockIdx.x;
    int e  = bid >> 6;
    int d0 = (bid & 63) * 32;

    int Me = counts[e];
    if (Me == 0) return;
    int off = offsets[e];

    int t = threadIdx.x;
    int lane = t & 63;
    int w = t >> 6;
    int wm = w >> 1, wn = w & 1;
    int l15 = lane & 15, lg = lane >> 4;

    const float* w2e = w2 + (size_t)e * FF * DIM + d0;

    // B staging role: thread -> (bcol, bk4); 4 fp32 loads/epoch
    int bcol = t & 31, bk4 = t >> 5;             // bk4 in [0,16)
    const float* bsrc = w2e + (size_t)(bk4 * 4) * DIM + bcol;
    int bsl  = bk4 >> 3;                         // k-slice
    int blgw = (bk4 >> 1) & 3;                   // lg of frag
    int boff = (bk4 & 1) * 4;                    // half within bf16x8
    int bch  = bcol + blgw * 32;

    const int NST = FF / BKE;                    // 64 epochs

    for (int mb = 0; mb < Me; mb += BM) {
        const unsigned short* arow[3];
#pragma unroll
        for (int f = 0; f < 3; ++f) {
            int rl = mb + wm * 48 + f * 16 + l15;
            int rr = (rl < Me) ? rl : (Me - 1);
            arow[f] = Hbuf + (size_t)(off + rr) * FF + lg * 8;
        }

        f32x4 acc[3];
#pragma unroll
        for (int f = 0; f < 3; ++f) acc[f] = (f32x4){0.f, 0.f, 0.f, 0.f};

        float bR[4];
        // prologue: B(0)
#pragma unroll
        for (int j = 0; j < 4; ++j) bR[j] = bsrc[(size_t)j * DIM];
        {
            bf16x4 wv;
#pragma unroll
            for (int j = 0; j < 4; ++j) wv[j] = f2bf(bR[j]);
            *(bf16x4*)&Bs[0][bsl][bch][boff] = wv;
        }
        __syncthreads();

        for (int s = 0; s < NST; ++s) {
            int cur = s & 1;
            bool more = (s + 1 < NST);

            bf16x8 aE[3], aO[3];
#pragma unroll
            for (int f = 0; f < 3; ++f) aE[f] = *(const bf16x8*)(arow[f] + s * BKE);
#pragma unroll
            for (int f = 0; f < 3; ++f) aO[f] = *(const bf16x8*)(arow[f] + s * BKE + 32);
            SCHEDBAR;

            if (more) {
#pragma unroll
                for (int j = 0; j < 4; ++j)
                    bR[j] = bsrc[(size_t)((s + 1) * BKE + j) * DIM];
            }

            {
                int ch = wn * 16 + l15 + lg * 32;
                bf16x8 b0 = *(const bf16x8*)&Bs[cur][0][ch][0];
                bf16x8 b1 = *(const bf16x8*)&Bs[cur][1][ch][0];
#pragma unroll
                for (int f = 0; f < 3; ++f) {
                    acc[f] = MFMA16(aE[f], b0, acc[f]);
                    acc[f] = MFMA16(aO[f], b1, acc[f]);
                }
            }

            if (more) {
                bf16x4 wv;
#pragma unroll
                for (int j = 0; j < 4; ++j) wv[j] = f2bf(bR[j]);
                *(bf16x4*)&Bs[cur ^ 1][bsl][bch][boff] = wv;
            }
            __syncthreads();
        }

#pragma unroll
        for (int f = 0; f < 3; ++f)
#pragma unroll
            for (int r = 0; r < 4; ++r) {
                int rl = mb + wm * 48 + f * 16 + lg * 4 + r;
                if (rl < Me) {
                    int grow = off + rl;
                    float g = row_gatew[grow];
                    OP[(size_t)grow * DIM + d0 + wn * 16 + l15] = acc[f][r] * g;
                }
            }
    }
}

// ---------------------------------------------------------------------------
// Kernel 5: out[token] = OP[pair0] + OP[pair1]
// ---------------------------------------------------------------------------
__global__ void combine(const float* __restrict__ OP, const int* __restrict__ pair_row,
                        float* __restrict__ out) {
    int idx = blockIdx.x * blockDim.x + threadIdx.x;
    int token = idx >> 9;
    int q = idx & 511;
    int r0 = pair_row[token * 2 + 0];
    int r1 = pair_row[token * 2 + 1];
    float4 a = *(const float4*)(OP + (size_t)r0 * DIM + q * 4);
    float4 b = *(const float4*)(OP + (size_t)r1 * DIM + q * 4);
    float4 o;
    o.x = a.x + b.x; o.y = a.y + b.y; o.z = a.z + b.z; o.w = a.w + b.w;
    *(float4*)(out + (size_t)token * DIM + q * 4) = o;
}

// ---------------------------------------------------------------------------
extern "C" void kernel_launch(void* const* d_in, const int* in_sizes, int n_in,
                              void* d_out, int out_size, void* d_ws, size_t ws_size,
                              hipStream_t stream) {
    const float* x  = (const float*)d_in[0];
    const float* gw = (const float*)d_in[1];
    const float* w1 = (const float*)d_in[2];
    const float* w3 = (const float*)d_in[3];
    const float* w2 = (const float*)d_in[4];
    float* out = (float*)d_out;

    char* ws = (char*)d_ws;
    unsigned short* Hbuf = (unsigned short*)ws;                 // 8 MB bf16 [1024][4096]
    float* OP            = (float*)(ws + 8388608);              // 8 MB f32  [1024][2048]
    unsigned short* xbf  = (unsigned short*)(ws + 16777216);    // 2 MB bf16 [512][2048]
    char* meta           = ws + 18874368;
    int*   tok_expert = (int*)(meta);
    float* tok_gatew  = (float*)(meta + 4096);
    int*   counts     = (int*)(meta + 8192);
    int*   offsets    = (int*)(meta + 8224);
    int*   row_token  = (int*)(meta + 8256);
    float* row_gatew  = (float*)(meta + 12352);
    int*   pair_row   = (int*)(meta + 16448);

    gate_topk<<<TOK, 64, 0, stream>>>(x, gw, xbf, tok_expert, tok_gatew);
    build_lists<<<1, 512, 0, stream>>>(tok_expert, tok_gatew, counts, offsets,
                                       row_token, row_gatew, pair_row);
    ffn1<<<NE * 64, 512, 0, stream>>>(xbf, w1, w3, counts, offsets, row_token, Hbuf);
    ffn2<<<NE * 64, 512, 0, stream>>>(Hbuf, w2, counts, offsets, row_gatew, OP);
    combine<<<1024, 256, 0, stream>>>(OP, pair_row, out);
}

// Round 9
// 276.878 us; speedup vs baseline: 1.1445x; 1.1445x over previous
//
#include <hip/hip_runtime.h>
#include <hip/hip_bf16.h>
#include <cstdint>
#include <cstddef>

// Problem constants
#define NB   64
#define NS   8
#define DIM  2048
#define FF   4096
#define NE   8
#define TOK  512            // NB*NS
#define NPAIR 1024          // TOK*2

// GEMM tiling
#define BM   256            // 8 M-waves x 32 rows; covers max Me (~200) in one pass
#define BN   32             // N-cols per block
#define BKE  64             // K per epoch (2 MFMA K-slices per barrier)

typedef __attribute__((ext_vector_type(4))) float f32x4;
typedef __attribute__((ext_vector_type(8))) short bf16x8;
typedef __attribute__((ext_vector_type(4))) short bf16x4;

#define MFMA16(a, b, c) __builtin_amdgcn_mfma_f32_16x16x32_bf16((a), (b), (c), 0, 0, 0)
#define SCHEDBAR __builtin_amdgcn_sched_barrier(0)
// raw barrier: drain LDS only; vmcnt prefetches stay in flight across it
#define LGKMBAR do { asm volatile("s_waitcnt lgkmcnt(0)" ::: "memory"); \
                     asm volatile("s_barrier" ::: "memory");            \
                     __builtin_amdgcn_sched_barrier(0); } while (0)

// round-half-up fp32 -> bf16 (0.5 ulp, 2 VALU ops)
static __device__ __forceinline__ short f2bf(float f) {
    unsigned u = __builtin_bit_cast(unsigned, f);
    return (short)((u + 0x8000u) >> 16);
}

// ---------------------------------------------------------------------------
// Kernel 1: gating (logits -> top-2 -> softmax) + x -> bf16 preconvert.
// ---------------------------------------------------------------------------
__global__ void gate_topk(const float* __restrict__ x, const float* __restrict__ gw,
                          unsigned short* __restrict__ xbf,
                          int* __restrict__ tok_expert, float* __restrict__ tok_gatew) {
    int token = blockIdx.x;
    int lane  = threadIdx.x;
    const float* xr = x + (size_t)token * DIM;

    float acc[NE];
#pragma unroll
    for (int e = 0; e < NE; ++e) acc[e] = 0.f;

    for (int d0 = lane * 8; d0 < DIM; d0 += 64 * 8) {
        float4 xa = *(const float4*)(xr + d0);
        float4 xb = *(const float4*)(xr + d0 + 4);
        bf16x8 v;
        v[0] = f2bf(xa.x); v[1] = f2bf(xa.y); v[2] = f2bf(xa.z); v[3] = f2bf(xa.w);
        v[4] = f2bf(xb.x); v[5] = f2bf(xb.y); v[6] = f2bf(xb.z); v[7] = f2bf(xb.w);
        *(bf16x8*)(xbf + (size_t)token * DIM + d0) = v;
#pragma unroll
        for (int j = 0; j < 8; ++j) {
            float xv = (j < 4) ? ((const float*)&xa)[j] : ((const float*)&xb)[j - 4];
            const float4* g = (const float4*)(gw + (size_t)(d0 + j) * NE);
            float4 g0 = g[0], g1 = g[1];
            acc[0] += xv * g0.x; acc[1] += xv * g0.y;
            acc[2] += xv * g0.z; acc[3] += xv * g0.w;
            acc[4] += xv * g1.x; acc[5] += xv * g1.y;
            acc[6] += xv * g1.z; acc[7] += xv * g1.w;
        }
    }
#pragma unroll
    for (int off = 32; off >= 1; off >>= 1) {
#pragma unroll
        for (int e = 0; e < NE; ++e) acc[e] += __shfl_down(acc[e], off);
    }
    if (lane == 0) {
        float b1 = -1e30f, b2 = -1e30f; int i1 = 0, i2 = 0;
#pragma unroll
        for (int e = 0; e < NE; ++e) {
            float v = acc[e];
            if (v > b1) { b2 = b1; i2 = i1; b1 = v; i1 = e; }
            else if (v > b2) { b2 = v; i2 = e; }
        }
        float t = __expf(b2 - b1);
        tok_expert[token * 2 + 0] = i1;
        tok_expert[token * 2 + 1] = i2;
        tok_gatew[token * 2 + 0] = 1.f / (1.f + t);
        tok_gatew[token * 2 + 1] = t / (1.f + t);
    }
}

// ---------------------------------------------------------------------------
// Kernel 2: deterministic per-expert token lists (wave-per-expert ballot scan)
// ---------------------------------------------------------------------------
__global__ void build_lists(const int* __restrict__ tok_expert,
                            const float* __restrict__ tok_gatew,
                            int* __restrict__ counts, int* __restrict__ offsets,
                            int* __restrict__ row_token, float* __restrict__ row_gatew,
                            int* __restrict__ pair_row) {
    __shared__ int s_off[NE];
    __shared__ int s_cnt[NE];
    int e    = threadIdx.x >> 6;
    int lane = threadIdx.x & 63;
    unsigned long long lt = (1ull << lane) - 1ull;

    int cnt = 0;
    for (int base = 0; base < NPAIR; base += 64) {
        int id = tok_expert[base + lane];
        unsigned long long m = __ballot(id == e);
        cnt += __popcll(m);
    }
    if (lane == 0) s_cnt[e] = cnt;
    __syncthreads();
    if (threadIdx.x == 0) {
        int o = 0;
        for (int i = 0; i < NE; ++i) {
            int c = s_cnt[i];
            counts[i] = c; offsets[i] = o; s_off[i] = o; o += c;
        }
    }
    __syncthreads();

    int rbase = s_off[e];
    for (int base = 0; base < NPAIR; base += 64) {
        int entry = base + lane;
        int id = tok_expert[entry];
        bool match = (id == e);
        unsigned long long m = __ballot(match);
        int pre = __popcll(m & lt);
        if (match) {
            int row = rbase + pre;
            row_token[row] = entry >> 1;
            row_gatew[row] = tok_gatew[entry];
            pair_row[entry] = row;
        }
        rbase += __popcll(m);
    }
}

// ---------------------------------------------------------------------------
// Kernel 3: H = silu(Xbf*w1) .* (Xbf*w3).  grid = 8 x 128 f-tiles (BN=32),
// 512 thr = 8 M-waves x 32 rows.  Distance-2 pipeline, FIFO-correct order:
//   issue A(s+1) | issue B(s+2) | MFMA(A(s), Bs) | cvt+write B(s+1) | lgkm+bar
// Every wait targets data issued >= 1 full epoch earlier -> zero stalls;
// raw barrier leaves vmcnt prefetches in flight.
// ---------------------------------------------------------------------------
#define EPOCH1(CUR, AC, AN, WS, LS, S, DO_AN, DO_L, DO_W) do {                \
    if (DO_AN) {                                                              \
        _Pragma("unroll")                                                     \
        for (int f = 0; f < 2; ++f) {                                         \
            AN[f]     = *(const bf16x8*)(arow[f] + ((S) + 1) * BKE);          \
            AN[2 + f] = *(const bf16x8*)(arow[f] + ((S) + 1) * BKE + 32);     \
        }                                                                     \
    }                                                                         \
    SCHEDBAR;                                                                 \
    if (DO_L) {                                                               \
        _Pragma("unroll")                                                     \
        for (int j = 0; j < 8; ++j)                                           \
            LS[j] = bsrc[(size_t)(((S) + 2) * BKE + j) * FF];                 \
    }                                                                         \
    SCHEDBAR;                                                                 \
    _Pragma("unroll")                                                         \
    for (int nf = 0; nf < 2; ++nf) {                                          \
        int ch = nf * 16 + l15 + lg * 32;                                     \
        bf16x8 b1f = *(const bf16x8*)&Bs[CUR][0][0][ch][0];                   \
        bf16x8 b3f = *(const bf16x8*)&Bs[CUR][1][0][ch][0];                   \
        _Pragma("unroll")                                                     \
        for (int f = 0; f < 2; ++f) {                                         \
            acc1[f][nf] = MFMA16(AC[f], b1f, acc1[f][nf]);                    \
            acc3[f][nf] = MFMA16(AC[f], b3f, acc3[f][nf]);                    \
        }                                                                     \
    }                                                                         \
    _Pragma("unroll")                                                         \
    for (int nf = 0; nf < 2; ++nf) {                                          \
        int ch = nf * 16 + l15 + lg * 32;                                     \
        bf16x8 b1f = *(const bf16x8*)&Bs[CUR][0][1][ch][0];                   \
        bf16x8 b3f = *(const bf16x8*)&Bs[CUR][1][1][ch][0];                   \
        _Pragma("unroll")                                                     \
        for (int f = 0; f < 2; ++f) {                                         \
            acc1[f][nf] = MFMA16(AC[2 + f], b1f, acc1[f][nf]);                \
            acc3[f][nf] = MFMA16(AC[2 + f], b3f, acc3[f][nf]);                \
        }                                                                     \
    }                                                                         \
    if (DO_W) {                                                               \
        bf16x8 wv;                                                            \
        _Pragma("unroll")                                                     \
        for (int j = 0; j < 8; ++j) wv[j] = f2bf(WS[j]);                      \
        *(bf16x8*)&Bs[(CUR) ^ 1][bmat][bsl][bch][0] = wv;                     \
    }                                                                         \
    LGKMBAR;                                                                  \
} while (0)

__global__ __launch_bounds__(512, 4) void ffn1(
    const unsigned short* __restrict__ xbf, const float* __restrict__ w1,
    const float* __restrict__ w3,
    const int* __restrict__ counts, const int* __restrict__ offsets,
    const int* __restrict__ row_token, unsigned short* __restrict__ Hbuf) {
    // [buf][mat][slice][chunk 128][8] : chunk = col + lg*32 (conflict-free)
    __shared__ __align__(16) unsigned short Bs[2][2][2][128][8];   // 16 KB

    int bid = blockIdx.x;
    int e  = bid >> 7;
    int f0 = (bid & 127) * BN;

    int Me = counts[e];
    if (Me == 0) return;
    int off = offsets[e];

    int t = threadIdx.x;
    int lane = t & 63;
    int wm = t >> 6;                             // 8 M-waves x 32 rows
    int l15 = lane & 15, lg = lane >> 4;

    const float* w1e = w1 + (size_t)e * DIM * FF + f0;
    const float* w3e = w3 + (size_t)e * DIM * FF + f0;

    // B staging role: one frag-chunk (8 fp32) per thread per epoch
    int bmat = t >> 8;                 // 0: w1, 1: w3
    int bc   = t & 255;
    int bsl  = bc >> 7;                // k-slice
    int blgw = (bc >> 5) & 3;          // lg of frag
    int bcol = bc & 31;
    const float* bsrc = (bmat ? w3e : w1e) + (size_t)(bsl * 32 + blgw * 8) * FF + bcol;
    int bch = bcol + blgw * 32;

    const int NST = DIM / BKE;                   // 32 epochs

    for (int mb = 0; mb < Me; mb += BM) {
        const unsigned short* arow[2];
#pragma unroll
        for (int f = 0; f < 2; ++f) {
            int rl = mb + wm * 32 + f * 16 + l15;
            int rr = (rl < Me) ? rl : (Me - 1);
            arow[f] = xbf + (size_t)row_token[off + rr] * DIM + lg * 8;
        }

        f32x4 acc1[2][2], acc3[2][2];
#pragma unroll
        for (int f = 0; f < 2; ++f)
#pragma unroll
            for (int nf = 0; nf < 2; ++nf) {
                acc1[f][nf] = (f32x4){0.f, 0.f, 0.f, 0.f};
                acc3[f][nf] = (f32x4){0.f, 0.f, 0.f, 0.f};
            }

        float bX[8], bY[8];
        bf16x8 aC[4], aN[4];

        // prologue: B(0)->LDS (one-time stall); issue A(0); issue X<-B(1)
#pragma unroll
        for (int j = 0; j < 8; ++j) bX[j] = bsrc[(size_t)j * FF];
        {
            bf16x8 wv;
#pragma unroll
            for (int j = 0; j < 8; ++j) wv[j] = f2bf(bX[j]);
            *(bf16x8*)&Bs[0][bmat][bsl][bch][0] = wv;
        }
#pragma unroll
        for (int f = 0; f < 2; ++f) {
            aC[f]     = *(const bf16x8*)(arow[f]);
            aC[2 + f] = *(const bf16x8*)(arow[f] + 32);
        }
        SCHEDBAR;
#pragma unroll
        for (int j = 0; j < 8; ++j) bX[j] = bsrc[(size_t)(BKE + j) * FF];
        LGKMBAR;

        for (int s = 0; s < NST - 2; s += 2) {
            EPOCH1(0, aC, aN, bX, bY, s, 1, 1, 1);
            EPOCH1(1, aN, aC, bY, bX, s + 1, 1, 1, 1);
        }
        EPOCH1(0, aC, aN, bX, bY, NST - 2, 1, 0, 1);
        EPOCH1(1, aN, aC, bY, bX, NST - 1, 0, 0, 0);

        // epilogue: silu(a1)*a3 -> bf16 H
#pragma unroll
        for (int f = 0; f < 2; ++f)
#pragma unroll
            for (int nf = 0; nf < 2; ++nf)
#pragma unroll
                for (int r = 0; r < 4; ++r) {
                    int rl = mb + wm * 32 + f * 16 + lg * 4 + r;
                    if (rl < Me) {
                        float a1 = acc1[f][nf][r], a3 = acc3[f][nf][r];
                        float h = (a1 / (1.f + __expf(-a1))) * a3;
                        Hbuf[(size_t)(off + rl) * FF + f0 + nf * 16 + l15] =
                            (unsigned short)f2bf(h);
                    }
                }
    }
}

// ---------------------------------------------------------------------------
// Kernel 4: OutPair = (H @ w2) * gate_weight.  grid = 8 x 64 d-tiles (BN=32),
// 512 thr, same distance-2 pipeline.  B: half-chunk (4 fp32) per thread.
// ---------------------------------------------------------------------------
#define EPOCH2(CUR, AC, AN, WS, LS, S, DO_AN, DO_L, DO_W) do {                \
    if (DO_AN) {                                                              \
        _Pragma("unroll")                                                     \
        for (int f = 0; f < 2; ++f) {                                         \
            AN[f]     = *(const bf16x8*)(arow[f] + ((S) + 1) * BKE);          \
            AN[2 + f] = *(const bf16x8*)(arow[f] + ((S) + 1) * BKE + 32);     \
        }                                                                     \
    }                                                                         \
    SCHEDBAR;                                                                 \
    if (DO_L) {                                                               \
        _Pragma("unroll")                                                     \
        for (int j = 0; j < 4; ++j)                                           \
            LS[j] = bsrc[(size_t)(((S) + 2) * BKE + j) * DIM];                \
    }                                                                         \
    SCHEDBAR;                                                                 \
    _Pragma("unroll")                                                         \
    for (int nf = 0; nf < 2; ++nf) {                                          \
        int ch = nf * 16 + l15 + lg * 32;                                     \
        bf16x8 b0 = *(const bf16x8*)&Bs[CUR][0][ch][0];                       \
        bf16x8 b1s = *(const bf16x8*)&Bs[CUR][1][ch][0];                      \
        _Pragma("unroll")                                                     \
        for (int f = 0; f < 2; ++f) {                                         \
            acc[f][nf] = MFMA16(AC[f], b0, acc[f][nf]);                       \
            acc[f][nf] = MFMA16(AC[2 + f], b1s, acc[f][nf]);                  \
        }                                                                     \
    }                                                                         \
    if (DO_W) {                                                               \
        bf16x4 wv;                                                            \
        _Pragma("unroll")                                                     \
        for (int j = 0; j < 4; ++j) wv[j] = f2bf(WS[j]);                      \
        *(bf16x4*)&Bs[(CUR) ^ 1][bsl][bch][bh * 4] = wv;                      \
    }                                                                         \
    LGKMBAR;                                                                  \
} while (0)

__global__ __launch_bounds__(512, 4) void ffn2(
    const unsigned short* __restrict__ Hbuf, const float* __restrict__ w2,
    const int* __restrict__ counts, const int* __restrict__ offsets,
    const float* __restrict__ row_gatew, float* __restrict__ OP) {
    // [buf][slice][chunk 128][8]
    __shared__ __align__(16) unsigned short Bs[2][2][128][8];      // 8 KB

    int bid = blockIdx.x;
    int e  = bid >> 6;
    int d0 = (bid & 63) * BN;

    int Me = counts[e];
    if (Me == 0) return;
    int off = offsets[e];

    int t = threadIdx.x;
    int lane = t & 63;
    int wm = t >> 6;
    int l15 = lane & 15, lg = lane >> 4;

    const float* w2e = w2 + (size_t)e * FF * DIM + d0;

    // B staging role: half frag-chunk (4 fp32) per thread per epoch
    int bc  = t >> 1, bh = t & 1;
    int bsl = bc >> 7;
    int blgw = (bc >> 5) & 3;
    int bcol = bc & 31;
    const float* bsrc = w2e + (size_t)(bsl * 32 + blgw * 8 + bh * 4) * DIM + bcol;
    int bch = bcol + blgw * 32;

    const int NST = FF / BKE;                    // 64 epochs

    for (int mb = 0; mb < Me; mb += BM) {
        const unsigned short* arow[2];
#pragma unroll
        for (int f = 0; f < 2; ++f) {
            int rl = mb + wm * 32 + f * 16 + l15;
            int rr = (rl < Me) ? rl : (Me - 1);
            arow[f] = Hbuf + (size_t)(off + rr) * FF + lg * 8;
        }

        f32x4 acc[2][2];
#pragma unroll
        for (int f = 0; f < 2; ++f)
#pragma unroll
            for (int nf = 0; nf < 2; ++nf) acc[f][nf] = (f32x4){0.f, 0.f, 0.f, 0.f};

        float bX[4], bY[4];
        bf16x8 aC[4], aN[4];

#pragma unroll
        for (int j = 0; j < 4; ++j) bX[j] = bsrc[(size_t)j * DIM];
        {
            bf16x4 wv;
#pragma unroll
            for (int j = 0; j < 4; ++j) wv[j] = f2bf(bX[j]);
            *(bf16x4*)&Bs[0][bsl][bch][bh * 4] = wv;
        }
#pragma unroll
        for (int f = 0; f < 2; ++f) {
            aC[f]     = *(const bf16x8*)(arow[f]);
            aC[2 + f] = *(const bf16x8*)(arow[f] + 32);
        }
        SCHEDBAR;
#pragma unroll
        for (int j = 0; j < 4; ++j) bX[j] = bsrc[(size_t)(BKE + j) * DIM];
        LGKMBAR;

        for (int s = 0; s < NST - 2; s += 2) {
            EPOCH2(0, aC, aN, bX, bY, s, 1, 1, 1);
            EPOCH2(1, aN, aC, bY, bX, s + 1, 1, 1, 1);
        }
        EPOCH2(0, aC, aN, bX, bY, NST - 2, 1, 0, 1);
        EPOCH2(1, aN, aC, bY, bX, NST - 1, 0, 0, 0);

#pragma unroll
        for (int f = 0; f < 2; ++f)
#pragma unroll
            for (int nf = 0; nf < 2; ++nf)
#pragma unroll
                for (int r = 0; r < 4; ++r) {
                    int rl = mb + wm * 32 + f * 16 + lg * 4 + r;
                    if (rl < Me) {
                        int grow = off + rl;
                        float g = row_gatew[grow];
                        OP[(size_t)grow * DIM + d0 + nf * 16 + l15] = acc[f][nf][r] * g;
                    }
                }
    }
}

// ---------------------------------------------------------------------------
// Kernel 5: out[token] = OP[pair0] + OP[pair1]
// ---------------------------------------------------------------------------
__global__ void combine(const float* __restrict__ OP, const int* __restrict__ pair_row,
                        float* __restrict__ out) {
    int idx = blockIdx.x * blockDim.x + threadIdx.x;
    int token = idx >> 9;
    int q = idx & 511;
    int r0 = pair_row[token * 2 + 0];
    int r1 = pair_row[token * 2 + 1];
    float4 a = *(const float4*)(OP + (size_t)r0 * DIM + q * 4);
    float4 b = *(const float4*)(OP + (size_t)r1 * DIM + q * 4);
    float4 o;
    o.x = a.x + b.x; o.y = a.y + b.y; o.z = a.z + b.z; o.w = a.w + b.w;
    *(float4*)(out + (size_t)token * DIM + q * 4) = o;
}

// ---------------------------------------------------------------------------
extern "C" void kernel_launch(void* const* d_in, const int* in_sizes, int n_in,
                              void* d_out, int out_size, void* d_ws, size_t ws_size,
                              hipStream_t stream) {
    const float* x  = (const float*)d_in[0];
    const float* gw = (const float*)d_in[1];
    const float* w1 = (const float*)d_in[2];
    const float* w3 = (const float*)d_in[3];
    const float* w2 = (const float*)d_in[4];
    float* out = (float*)d_out;

    char* ws = (char*)d_ws;
    unsigned short* Hbuf = (unsigned short*)ws;                 // 8 MB bf16 [1024][4096]
    float* OP            = (float*)(ws + 8388608);              // 8 MB f32  [1024][2048]
    unsigned short* xbf  = (unsigned short*)(ws + 16777216);    // 2 MB bf16 [512][2048]
    char* meta           = ws + 18874368;
    int*   tok_expert = (int*)(meta);
    float* tok_gatew  = (float*)(meta + 4096);
    int*   counts     = (int*)(meta + 8192);
    int*   offsets    = (int*)(meta + 8224);
    int*   row_token  = (int*)(meta + 8256);
    float* row_gatew  = (float*)(meta + 12352);
    int*   pair_row   = (int*)(meta + 16448);

    gate_topk<<<TOK, 64, 0, stream>>>(x, gw, xbf, tok_expert, tok_gatew);
    build_lists<<<1, 512, 0, stream>>>(tok_expert, tok_gatew, counts, offsets,
                                       row_token, row_gatew, pair_row);
    ffn1<<<NE * 128, 512, 0, stream>>>(xbf, w1, w3, counts, offsets, row_token, Hbuf);
    ffn2<<<NE * 64, 512, 0, stream>>>(Hbuf, w2, counts, offsets, row_gatew, OP);
    combine<<<1024, 256, 0, stream>>>(OP, pair_row, out);
}

// Round 10
// 238.708 us; speedup vs baseline: 1.3275x; 1.1599x over previous
//
#include <hip/hip_runtime.h>
#include <hip/hip_bf16.h>
#include <cstdint>
#include <cstddef>

// Problem constants
#define NB   64
#define NS   8
#define DIM  2048
#define FF   4096
#define NE   8
#define TOK  512            // NB*NS
#define NPAIR 1024          // TOK*2

// GEMM tiling
#define BM   192            // 4 M-waves x 48 rows; covers max Me (~180) in one pass
#define BN   64             // N-cols per block (2 N-waves x 32)
#define BKE  32             // K per epoch (one 16x16x32 MFMA K-slice)

typedef __attribute__((ext_vector_type(4))) float f32x4;
typedef __attribute__((ext_vector_type(8))) short bf16x8;
typedef __attribute__((ext_vector_type(4))) short bf16x4;

#define MFMA16(a, b, c) __builtin_amdgcn_mfma_f32_16x16x32_bf16((a), (b), (c), 0, 0, 0)
#define SCHEDBAR __builtin_amdgcn_sched_barrier(0)
#define VMCNT8  asm volatile("s_waitcnt vmcnt(8)" ::: "memory")
#define VMCNT4  asm volatile("s_waitcnt vmcnt(4)" ::: "memory")
#define VMCNT0  asm volatile("s_waitcnt vmcnt(0)" ::: "memory")
// raw barrier: drain LDS only; vmcnt prefetches stay in flight across it
#define LGKMBAR do { asm volatile("s_waitcnt lgkmcnt(0)" ::: "memory"); \
                     asm volatile("s_barrier" ::: "memory");            \
                     __builtin_amdgcn_sched_barrier(0); } while (0)

// round-half-up fp32 -> bf16 (0.5 ulp, 2 VALU ops)
static __device__ __forceinline__ short f2bf(float f) {
    unsigned u = __builtin_bit_cast(unsigned, f);
    return (short)((u + 0x8000u) >> 16);
}

// async global->LDS DMA, 16 bytes/lane; LDS dest wave-linear (base+lane*16),
// global source per-lane arbitrary (swizzle the SOURCE, never the dest).
static __device__ __forceinline__ void async16(void* l, const void* g) {
    __builtin_amdgcn_global_load_lds(
        (const __attribute__((address_space(1))) void*)g,
        (__attribute__((address_space(3))) void*)l, 16, 0, 0);
}

// ---------------------------------------------------------------------------
// Kernel 1: gating (logits -> top-2 -> softmax) + x -> bf16 preconvert.
// ---------------------------------------------------------------------------
__global__ void gate_topk(const float* __restrict__ x, const float* __restrict__ gw,
                          unsigned short* __restrict__ xbf,
                          int* __restrict__ tok_expert, float* __restrict__ tok_gatew) {
    int token = blockIdx.x;
    int lane  = threadIdx.x;
    const float* xr = x + (size_t)token * DIM;

    float acc[NE];
#pragma unroll
    for (int e = 0; e < NE; ++e) acc[e] = 0.f;

    for (int d0 = lane * 8; d0 < DIM; d0 += 64 * 8) {
        float4 xa = *(const float4*)(xr + d0);
        float4 xb = *(const float4*)(xr + d0 + 4);
        bf16x8 v;
        v[0] = f2bf(xa.x); v[1] = f2bf(xa.y); v[2] = f2bf(xa.z); v[3] = f2bf(xa.w);
        v[4] = f2bf(xb.x); v[5] = f2bf(xb.y); v[6] = f2bf(xb.z); v[7] = f2bf(xb.w);
        *(bf16x8*)(xbf + (size_t)token * DIM + d0) = v;
#pragma unroll
        for (int j = 0; j < 8; ++j) {
            float xv = (j < 4) ? ((const float*)&xa)[j] : ((const float*)&xb)[j - 4];
            const float4* g = (const float4*)(gw + (size_t)(d0 + j) * NE);
            float4 g0 = g[0], g1 = g[1];
            acc[0] += xv * g0.x; acc[1] += xv * g0.y;
            acc[2] += xv * g0.z; acc[3] += xv * g0.w;
            acc[4] += xv * g1.x; acc[5] += xv * g1.y;
            acc[6] += xv * g1.z; acc[7] += xv * g1.w;
        }
    }
#pragma unroll
    for (int off = 32; off >= 1; off >>= 1) {
#pragma unroll
        for (int e = 0; e < NE; ++e) acc[e] += __shfl_down(acc[e], off);
    }
    if (lane == 0) {
        float b1 = -1e30f, b2 = -1e30f; int i1 = 0, i2 = 0;
#pragma unroll
        for (int e = 0; e < NE; ++e) {
            float v = acc[e];
            if (v > b1) { b2 = b1; i2 = i1; b1 = v; i1 = e; }
            else if (v > b2) { b2 = v; i2 = e; }
        }
        float t = __expf(b2 - b1);
        tok_expert[token * 2 + 0] = i1;
        tok_expert[token * 2 + 1] = i2;
        tok_gatew[token * 2 + 0] = 1.f / (1.f + t);
        tok_gatew[token * 2 + 1] = t / (1.f + t);
    }
}

// ---------------------------------------------------------------------------
// Kernel 2: deterministic per-expert token lists (wave-per-expert ballot scan)
// ---------------------------------------------------------------------------
__global__ void build_lists(const int* __restrict__ tok_expert,
                            const float* __restrict__ tok_gatew,
                            int* __restrict__ counts, int* __restrict__ offsets,
                            int* __restrict__ row_token, float* __restrict__ row_gatew,
                            int* __restrict__ pair_row) {
    __shared__ int s_off[NE];
    __shared__ int s_cnt[NE];
    int e    = threadIdx.x >> 6;
    int lane = threadIdx.x & 63;
    unsigned long long lt = (1ull << lane) - 1ull;

    int cnt = 0;
    for (int base = 0; base < NPAIR; base += 64) {
        int id = tok_expert[base + lane];
        unsigned long long m = __ballot(id == e);
        cnt += __popcll(m);
    }
    if (lane == 0) s_cnt[e] = cnt;
    __syncthreads();
    if (threadIdx.x == 0) {
        int o = 0;
        for (int i = 0; i < NE; ++i) {
            int c = s_cnt[i];
            counts[i] = c; offsets[i] = o; s_off[i] = o; o += c;
        }
    }
    __syncthreads();

    int rbase = s_off[e];
    for (int base = 0; base < NPAIR; base += 64) {
        int entry = base + lane;
        int id = tok_expert[entry];
        bool match = (id == e);
        unsigned long long m = __ballot(match);
        int pre = __popcll(m & lt);
        if (match) {
            int row = rbase + pre;
            row_token[row] = entry >> 1;
            row_gatew[row] = tok_gatew[entry];
            pair_row[entry] = row;
        }
        rbase += __popcll(m);
    }
}

// ---------------------------------------------------------------------------
// Kernel 3: H = silu(Xbf*w1) .* (Xbf*w3).  grid = 8 x 64 f-tiles (BN=64),
// 512 thr = 4M x 2N waves.  A: global_load_lds DMA (shared by N-waves),
// source-chunk swizzle (c-(m>>1))&3 -> reads at (lg+(r>>1))&3 are 2-way free.
// B: reg-staged (8 k-strided dwords/thread), frag-major LDS, distance-2.
// Epoch: DMA(s+1) | B(s+2) | MFMA | cvt+write B(s+1) | vmcnt(8) | lgkm+bar.
// ---------------------------------------------------------------------------
#define EP1(CUR, WS, LS, S, HAS_DMA, HAS_L, HAS_W, VMW) do {                  \
    if (HAS_DMA) {                                                            \
        async16(&As[CUR ^ 1][(size_t)t * 8], asrc0 + ((S) + 1) * BKE);        \
        if (t < 256)                                                          \
            async16(&As[CUR ^ 1][(size_t)(512 + t) * 8],                      \
                    asrc1 + ((S) + 1) * BKE);                                 \
    }                                                                         \
    SCHEDBAR;                                                                 \
    if (HAS_L) {                                                              \
        _Pragma("unroll")                                                     \
        for (int j = 0; j < 8; ++j)                                           \
            LS[j] = bsrc[(size_t)(((S) + 2) * BKE + j) * FF];                 \
    }                                                                         \
    SCHEDBAR;                                                                 \
    bf16x8 a_[3];                                                             \
    _Pragma("unroll")                                                         \
    for (int f = 0; f < 3; ++f) {                                             \
        int r_ = wm * 48 + f * 16 + l15;                                      \
        int p_ = (lg + (r_ >> 1)) & 3;                                        \
        a_[f] = *(const bf16x8*)&As[CUR][((size_t)r_ * 4 + p_) * 8];          \
    }                                                                         \
    _Pragma("unroll")                                                         \
    for (int nf = 0; nf < 2; ++nf) {                                          \
        int ch_ = wn * 32 + nf * 16 + l15 + lg * 64;                          \
        bf16x8 b1f = *(const bf16x8*)&Bs[CUR][0][ch_][0];                     \
        bf16x8 b3f = *(const bf16x8*)&Bs[CUR][1][ch_][0];                     \
        _Pragma("unroll")                                                     \
        for (int f = 0; f < 3; ++f) {                                         \
            acc1[f][nf] = MFMA16(a_[f], b1f, acc1[f][nf]);                    \
            acc3[f][nf] = MFMA16(a_[f], b3f, acc3[f][nf]);                    \
        }                                                                     \
    }                                                                         \
    if (HAS_W) {                                                              \
        bf16x8 wv;                                                            \
        _Pragma("unroll")                                                     \
        for (int j = 0; j < 8; ++j) wv[j] = f2bf(WS[j]);                      \
        *(bf16x8*)&Bs[CUR ^ 1][bmat][bch][0] = wv;                            \
    }                                                                         \
    VMW;                                                                      \
    LGKMBAR;                                                                  \
} while (0)

__global__ __launch_bounds__(512, 4) void ffn1(
    const unsigned short* __restrict__ xbf, const float* __restrict__ w1,
    const float* __restrict__ w3,
    const int* __restrict__ counts, const int* __restrict__ offsets,
    const int* __restrict__ row_token, unsigned short* __restrict__ Hbuf) {
    __shared__ __align__(16) unsigned short As[2][BM * 4 * 8];     // 24 KB
    __shared__ __align__(16) unsigned short Bs[2][2][256][8];      // 16 KB

    int bid = blockIdx.x;
    int e  = bid >> 6;
    int f0 = (bid & 63) * BN;

    int Me = counts[e];
    if (Me == 0) return;
    int off = offsets[e];

    int t = threadIdx.x;
    int lane = t & 63;
    int w = t >> 6;
    int wm = w >> 1, wn = w & 1;                 // 4 M-waves x 2 N-waves
    int l15 = lane & 15, lg = lane >> 4;

    const float* w1e = w1 + (size_t)e * DIM * FF + f0;
    const float* w3e = w3 + (size_t)e * DIM * FF + f0;

    // B staging role: one frag-chunk (8 k-strided fp32) per thread per epoch
    int bmat = t >> 8;                 // 0: w1, 1: w3
    int bc   = t & 255;
    int bcol = bc & 63, blg = bc >> 6;
    const float* bsrc = (bmat ? w3e : w1e) + (size_t)(blg * 8) * FF + bcol;
    int bch = bcol + blg * 64;

    const int NST = DIM / BKE;                   // 64 epochs

    for (int mb = 0; mb < Me; mb += BM) {
        __syncthreads();
        // A DMA sources: chunk i -> (m = i>>2, c = i&3); source chunk
        // (c - (m>>1)) & 3 (read at position (lg + (r>>1))&3 -> 2-way free)
        const unsigned short* asrc0;
        const unsigned short* asrc1;
        {
            int m0 = t >> 2, c0 = t & 3;
            int rl0 = mb + m0;
            int tok0 = row_token[off + ((rl0 < Me) ? rl0 : (Me - 1))];
            asrc0 = xbf + (size_t)tok0 * DIM + (((c0 - (m0 >> 1)) & 3) << 3);
            int i1 = 512 + t;
            int m1 = i1 >> 2, c1 = i1 & 3;
            int rl1 = mb + m1;
            int tok1 = row_token[off + ((rl1 < Me) ? rl1 : (Me - 1))];
            asrc1 = xbf + (size_t)tok1 * DIM + (((c1 - (m1 >> 1)) & 3) << 3);
        }

        f32x4 acc1[3][2], acc3[3][2];
#pragma unroll
        for (int f = 0; f < 3; ++f)
#pragma unroll
            for (int nf = 0; nf < 2; ++nf) {
                acc1[f][nf] = (f32x4){0.f, 0.f, 0.f, 0.f};
                acc3[f][nf] = (f32x4){0.f, 0.f, 0.f, 0.f};
            }

        float bX[8], bY[8];

        // prologue: DMA A(0); B(0) -> regs -> Bs[0] (one-time drain); B(1)
        async16(&As[0][(size_t)t * 8], asrc0);
        if (t < 256) async16(&As[0][(size_t)(512 + t) * 8], asrc1);
        SCHEDBAR;
#pragma unroll
        for (int j = 0; j < 8; ++j) bX[j] = bsrc[(size_t)j * FF];
        {
            bf16x8 wv;
#pragma unroll
            for (int j = 0; j < 8; ++j) wv[j] = f2bf(bX[j]);
            *(bf16x8*)&Bs[0][bmat][bch][0] = wv;
        }
#pragma unroll
        for (int j = 0; j < 8; ++j) bX[j] = bsrc[(size_t)(BKE + j) * FF];
        LGKMBAR;

        for (int s = 0; s < NST - 2; s += 2) {
            EP1(0, bX, bY, s,     1, 1, 1, VMCNT8);
            EP1(1, bY, bX, s + 1, 1, 1, 1, VMCNT8);
        }
        EP1(0, bX, bY, NST - 2, 1, 0, 1, VMCNT0);
        EP1(1, bY, bX, NST - 1, 0, 0, 0, (void)0);

        // epilogue: silu(a1)*a3 -> bf16 H
#pragma unroll
        for (int f = 0; f < 3; ++f)
#pragma unroll
            for (int nf = 0; nf < 2; ++nf)
#pragma unroll
                for (int r = 0; r < 4; ++r) {
                    int rl = mb + wm * 48 + f * 16 + lg * 4 + r;
                    if (rl < Me) {
                        float a1 = acc1[f][nf][r], a3 = acc3[f][nf][r];
                        float h = (a1 / (1.f + __expf(-a1))) * a3;
                        Hbuf[(size_t)(off + rl) * FF + f0 + wn * 32 + nf * 16 + l15] =
                            (unsigned short)f2bf(h);
                    }
                }
    }
}

// ---------------------------------------------------------------------------
// Kernel 4: OutPair = (H @ w2) * gate_weight.  grid = 8 x 32 d-tiles (BN=64),
// 512 thr, same structure (A DMA'd Hbuf, B half-chunk 4 dwords/thread).
// ---------------------------------------------------------------------------
#define EP2(CUR, WS, LS, S, HAS_DMA, HAS_L, HAS_W, VMW) do {                  \
    if (HAS_DMA) {                                                            \
        async16(&As[CUR ^ 1][(size_t)t * 8], asrc0 + ((S) + 1) * BKE);        \
        if (t < 256)                                                          \
            async16(&As[CUR ^ 1][(size_t)(512 + t) * 8],                      \
                    asrc1 + ((S) + 1) * BKE);                                 \
    }                                                                         \
    SCHEDBAR;                                                                 \
    if (HAS_L) {                                                              \
        _Pragma("unroll")                                                     \
        for (int j = 0; j < 4; ++j)                                           \
            LS[j] = bsrc[(size_t)(((S) + 2) * BKE + j) * DIM];                \
    }                                                                         \
    SCHEDBAR;                                                                 \
    bf16x8 a_[3];                                                             \
    _Pragma("unroll")                                                         \
    for (int f = 0; f < 3; ++f) {                                             \
        int r_ = wm * 48 + f * 16 + l15;                                      \
        int p_ = (lg + (r_ >> 1)) & 3;                                        \
        a_[f] = *(const bf16x8*)&As[CUR][((size_t)r_ * 4 + p_) * 8];          \
    }                                                                         \
    _Pragma("unroll")                                                         \
    for (int nf = 0; nf < 2; ++nf) {                                          \
        int ch_ = wn * 32 + nf * 16 + l15 + lg * 64;                          \
        bf16x8 bw = *(const bf16x8*)&Bs[CUR][ch_][0];                         \
        _Pragma("unroll")                                                     \
        for (int f = 0; f < 3; ++f)                                           \
            acc[f][nf] = MFMA16(a_[f], bw, acc[f][nf]);                       \
    }                                                                         \
    if (HAS_W) {                                                              \
        bf16x4 wv;                                                            \
        _Pragma("unroll")                                                     \
        for (int j = 0; j < 4; ++j) wv[j] = f2bf(WS[j]);                      \
        *(bf16x4*)&Bs[CUR ^ 1][bch][bhalf * 4] = wv;                          \
    }                                                                         \
    VMW;                                                                      \
    LGKMBAR;                                                                  \
} while (0)

__global__ __launch_bounds__(512, 4) void ffn2(
    const unsigned short* __restrict__ Hbuf, const float* __restrict__ w2,
    const int* __restrict__ counts, const int* __restrict__ offsets,
    const float* __restrict__ row_gatew, float* __restrict__ OP) {
    __shared__ __align__(16) unsigned short As[2][BM * 4 * 8];     // 24 KB
    __shared__ __align__(16) unsigned short Bs[2][256][8];         //  8 KB

    int bid = blockIdx.x;
    int e  = bid >> 5;
    int d0 = (bid & 31) * BN;

    int Me = counts[e];
    if (Me == 0) return;
    int off = offsets[e];

    int t = threadIdx.x;
    int lane = t & 63;
    int w = t >> 6;
    int wm = w >> 1, wn = w & 1;
    int l15 = lane & 15, lg = lane >> 4;

    const float* w2e = w2 + (size_t)e * FF * DIM + d0;

    // B staging role: half frag-chunk (4 k-strided fp32) per thread
    int bcol = t & 63, blg = (t >> 6) & 3, bhalf = t >> 8;
    const float* bsrc = w2e + (size_t)(blg * 8 + bhalf * 4) * DIM + bcol;
    int bch = bcol + blg * 64;

    const int NST = FF / BKE;                    // 128 epochs

    for (int mb = 0; mb < Me; mb += BM) {
        __syncthreads();
        const unsigned short* asrc0;
        const unsigned short* asrc1;
        {
            int m0 = t >> 2, c0 = t & 3;
            int rl0 = mb + m0;
            asrc0 = Hbuf + (size_t)(off + ((rl0 < Me) ? rl0 : (Me - 1))) * FF
                         + (((c0 - (m0 >> 1)) & 3) << 3);
            int i1 = 512 + t;
            int m1 = i1 >> 2, c1 = i1 & 3;
            int rl1 = mb + m1;
            asrc1 = Hbuf + (size_t)(off + ((rl1 < Me) ? rl1 : (Me - 1))) * FF
                         + (((c1 - (m1 >> 1)) & 3) << 3);
        }

        f32x4 acc[3][2];
#pragma unroll
        for (int f = 0; f < 3; ++f)
#pragma unroll
            for (int nf = 0; nf < 2; ++nf) acc[f][nf] = (f32x4){0.f, 0.f, 0.f, 0.f};

        float bX[4], bY[4];

        async16(&As[0][(size_t)t * 8], asrc0);
        if (t < 256) async16(&As[0][(size_t)(512 + t) * 8], asrc1);
        SCHEDBAR;
#pragma unroll
        for (int j = 0; j < 4; ++j) bX[j] = bsrc[(size_t)j * DIM];
        {
            bf16x4 wv;
#pragma unroll
            for (int j = 0; j < 4; ++j) wv[j] = f2bf(bX[j]);
            *(bf16x4*)&Bs[0][bch][bhalf * 4] = wv;
        }
#pragma unroll
        for (int j = 0; j < 4; ++j) bX[j] = bsrc[(size_t)(BKE + j) * DIM];
        LGKMBAR;

        for (int s = 0; s < NST - 2; s += 2) {
            EP2(0, bX, bY, s,     1, 1, 1, VMCNT4);
            EP2(1, bY, bX, s + 1, 1, 1, 1, VMCNT4);
        }
        EP2(0, bX, bY, NST - 2, 1, 0, 1, VMCNT0);
        EP2(1, bY, bX, NST - 1, 0, 0, 0, (void)0);

#pragma unroll
        for (int f = 0; f < 3; ++f)
#pragma unroll
            for (int nf = 0; nf < 2; ++nf)
#pragma unroll
                for (int r = 0; r < 4; ++r) {
                    int rl = mb + wm * 48 + f * 16 + lg * 4 + r;
                    if (rl < Me) {
                        int grow = off + rl;
                        float g = row_gatew[grow];
                        OP[(size_t)grow * DIM + d0 + wn * 32 + nf * 16 + l15] =
                            acc[f][nf][r] * g;
                    }
                }
    }
}

// ---------------------------------------------------------------------------
// Kernel 5: out[token] = OP[pair0] + OP[pair1]
// ---------------------------------------------------------------------------
__global__ void combine(const float* __restrict__ OP, const int* __restrict__ pair_row,
                        float* __restrict__ out) {
    int idx = blockIdx.x * blockDim.x + threadIdx.x;
    int token = idx >> 9;
    int q = idx & 511;
    int r0 = pair_row[token * 2 + 0];
    int r1 = pair_row[token * 2 + 1];
    float4 a = *(const float4*)(OP + (size_t)r0 * DIM + q * 4);
    float4 b = *(const float4*)(OP + (size_t)r1 * DIM + q * 4);
    float4 o;
    o.x = a.x + b.x; o.y = a.y + b.y; o.z = a.z + b.z; o.w = a.w + b.w;
    *(float4*)(out + (size_t)token * DIM + q * 4) = o;
}

// ---------------------------------------------------------------------------
extern "C" void kernel_launch(void* const* d_in, const int* in_sizes, int n_in,
                              void* d_out, int out_size, void* d_ws, size_t ws_size,
                              hipStream_t stream) {
    const float* x  = (const float*)d_in[0];
    const float* gw = (const float*)d_in[1];
    const float* w1 = (const float*)d_in[2];
    const float* w3 = (const float*)d_in[3];
    const float* w2 = (const float*)d_in[4];
    float* out = (float*)d_out;

    char* ws = (char*)d_ws;
    unsigned short* Hbuf = (unsigned short*)ws;                 // 8 MB bf16 [1024][4096]
    float* OP            = (float*)(ws + 8388608);              // 8 MB f32  [1024][2048]
    unsigned short* xbf  = (unsigned short*)(ws + 16777216);    // 2 MB bf16 [512][2048]
    char* meta           = ws + 18874368;
    int*   tok_expert = (int*)(meta);
    float* tok_gatew  = (float*)(meta + 4096);
    int*   counts     = (int*)(meta + 8192);
    int*   offsets    = (int*)(meta + 8224);
    int*   row_token  = (int*)(meta + 8256);
    float* row_gatew  = (float*)(meta + 12352);
    int*   pair_row   = (int*)(meta + 16448);

    gate_topk<<<TOK, 64, 0, stream>>>(x, gw, xbf, tok_expert, tok_gatew);
    build_lists<<<1, 512, 0, stream>>>(tok_expert, tok_gatew, counts, offsets,
                                       row_token, row_gatew, pair_row);
    ffn1<<<NE * 64, 512, 0, stream>>>(xbf, w1, w3, counts, offsets, row_token, Hbuf);
    ffn2<<<NE * 32, 512, 0, stream>>>(Hbuf, w2, counts, offsets, row_gatew, OP);
    combine<<<1024, 256, 0, stream>>>(OP, pair_row, out);
}